// Round 7
// baseline (379.794 us; speedup 1.0000x reference)
//
#include <hip/hip_runtime.h>
#include <math.h>

#define NPIX (2048*2048)
#define NBLOCKS 1024           // 4 blocks/CU, all resident in one round (best cfg, R3)
#define CHUNK (NPIX/NBLOCKS)   // 4096 px per block
#define SPX 256
#define NSTEP (CHUNK/SPX)      // 16

// global ws: NREP replicas of the 2305-float accumulator table, stride RSTRIDE
// floats (9728 B, line-aligned). Proven layout:
//  T0 [0,1024):    [64 l][16 c], 2x: c0..7=2*seg[c][l], c8..15=2*T[c][l]
//  T1 [1024,2048): col 8 = 2*pck[l]
//  T2 [2048,2304): radix [16 lo][16 hi], 4*pcr[lo+16*hi]
//  [2304] = 2x f2
#define WS_T1 1024
#define WS_T2 2048
#define WS_F2 2304
#define WS_FLOATS 2305
#define NREP 32
#define RSTRIDE 2432
#define L_T1 1088
#define L_T2 2176
#define LDS_RED (2176 + 16*17)

typedef __attribute__((ext_vector_type(8))) short short8;
typedef __attribute__((ext_vector_type(4))) float f32x4;
typedef __attribute__((ext_vector_type(4))) unsigned int u32x4;

__device__ __forceinline__ unsigned int pk_trunc_bf16(float lo, float hi) {
    return __builtin_amdgcn_perm(__float_as_uint(hi), __float_as_uint(lo), 0x07060302u);
}
__device__ __forceinline__ unsigned int pk_lab(int lo, int hi) {
    return __builtin_amdgcn_perm((unsigned)hi, (unsigned)lo, 0x05040100u);
}
__device__ __forceinline__ unsigned int onehot2(unsigned int x, unsigned int tp) {
    const unsigned int a = x ^ tp;
    const unsigned int t = 0x40004000u - a;
    return t & 0x40004000u;
}

// ---------- shared helpers for probe_valu (same arithmetic as main loop) ----
struct Frag { float4 pa, pb; int4 ka, kb, ra, rb; };

__device__ __forceinline__ void loadf0(Frag& F, const float* pp, const int* kp,
                                       const int* rp) {
    F.pa = *(const float4*)(pp);
    F.pb = *(const float4*)(pp + 4);
    F.ka = *(const int4*)(kp);
    F.kb = *(const int4*)(kp + 4);
    F.ra = *(const int4*)(rp);
    F.rb = *(const int4*)(rp + 4);
}

__device__ __forceinline__ void compute32(
    const Frag& F, bool lowcol, unsigned int cpack,
    const unsigned int (&tps)[4], const short8& b2c,
    f32x4 (&acc0)[4], f32x4 (&acc1)[4], f32x4& acc2, float& f2)
{
    const int   klv[8] = {F.ka.x, F.ka.y, F.ka.z, F.ka.w, F.kb.x, F.kb.y, F.kb.z, F.kb.w};
    const int   rlv[8] = {F.ra.x, F.ra.y, F.ra.z, F.ra.w, F.rb.x, F.rb.y, F.rb.z, F.rb.w};
    const float pv[8]  = {F.pa.x, F.pa.y, F.pa.z, F.pa.w, F.pb.x, F.pb.y, F.pb.z, F.pb.w};
    float pr[8];
    #pragma unroll
    for (int j = 0; j < 8; ++j) {
        pr[j] = (rlv[j] > 0) ? pv[j] : 0.f;
        f2 = fmaf(pr[j], pr[j], f2);
    }
    unsigned int b1p[4], kp4[4], rp4[4];
    #pragma unroll
    for (int q = 0; q < 4; ++q) {
        const int j0 = 2 * q, j1 = 2 * q + 1;
        const unsigned int plo = pk_trunc_bf16(pv[j0], pv[j1]);
        const unsigned int phi = pk_trunc_bf16(pr[j0], pr[j1]);
        b1p[q] = lowcol ? plo : phi;
        kp4[q] = pk_lab(klv[j0], klv[j1]);
        rp4[q] = pk_lab(rlv[j0], rlv[j1]);
    }
    const short8 b1 = __builtin_bit_cast(short8,
        (u32x4){b1p[0], b1p[1], b1p[2], b1p[3]});
    #pragma unroll
    for (int t = 0; t < 4; ++t) {
        u32x4 oh;
        #pragma unroll
        for (int q = 0; q < 4; ++q) oh[q] = onehot2(kp4[q], tps[t]);
        const short8 ak = __builtin_bit_cast(short8, oh);
        acc0[t] = __builtin_amdgcn_mfma_f32_16x16x32_bf16(ak, b1,  acc0[t], 0, 0, 0);
        acc1[t] = __builtin_amdgcn_mfma_f32_16x16x32_bf16(ak, b2c, acc1[t], 0, 0, 0);
    }
    u32x4 alo, bhi;
    #pragma unroll
    for (int q = 0; q < 4; ++q) {
        alo[q] = onehot2(rp4[q] & 0x000F000Fu, cpack);
        bhi[q] = onehot2((rp4[q] >> 4) & 0x00030003u, cpack);
    }
    acc2 = __builtin_amdgcn_mfma_f32_16x16x32_bf16(
        __builtin_bit_cast(short8, alo), __builtin_bit_cast(short8, bhi),
        acc2, 0, 0, 0);
}

// ---------- DIAGNOSTIC PROBE 1: loads only, same addresses/loop as agg_mfma.
// Runs BEFORE the ws memset; its writes are erased. XOR-consume defeats DCE.
__global__ __launch_bounds__(256, 4) void probe_loads(
    const float* __restrict__ pred, const int* __restrict__ kl,
    const int* __restrict__ rl, float* __restrict__ ws)
{
    const int tid = threadIdx.x, wv = tid >> 6, lane = tid & 63;
    const int quad = lane >> 4, col = lane & 15, c8 = col & 7;
    const int P0 = blockIdx.x * CHUNK;
    const int pbase = (2 * wv) * 32 + quad * 8;
    const float* pp = pred + (size_t)c8 * NPIX + P0 + pbase;
    const int*   kp = kl + P0 + pbase;
    const int*   rp = rl + P0 + pbase;

    unsigned int acc = 0;
    #pragma unroll 4
    for (int s = 0; s < NSTEP; ++s) {
        #pragma unroll
        for (int i = 0; i < 2; ++i) {
            const int off = s * SPX + i * 32;
            const float4 pa  = *(const float4*)(pp + off);
            const float4 pb4 = *(const float4*)(pp + off + 4);
            const int4   ka  = *(const int4*)(kp + off);
            const int4   kb  = *(const int4*)(kp + off + 4);
            const int4   ra  = *(const int4*)(rp + off);
            const int4   rb  = *(const int4*)(rp + off + 4);
            acc ^= __float_as_uint(pa.x) ^ __float_as_uint(pa.y)
                 ^ __float_as_uint(pa.z) ^ __float_as_uint(pa.w)
                 ^ __float_as_uint(pb4.x) ^ __float_as_uint(pb4.y)
                 ^ __float_as_uint(pb4.z) ^ __float_as_uint(pb4.w);
            acc ^= (unsigned)(ka.x ^ ka.y ^ ka.z ^ ka.w)
                 ^ (unsigned)(kb.x ^ kb.y ^ kb.z ^ kb.w)
                 ^ (unsigned)(ra.x ^ ra.y ^ ra.z ^ ra.w)
                 ^ (unsigned)(rb.x ^ rb.y ^ rb.z ^ rb.w);
        }
    }
    #pragma unroll
    for (int off = 32; off > 0; off >>= 1)
        acc ^= (unsigned)__shfl_down((int)acc, off, 64);
    if (lane == 0) atomicAdd(&ws[wv], (float)(acc & 1));
}

// ---------- DIAGNOSTIC PROBE 2: full compute mix from registers, no loop loads.
__global__ __launch_bounds__(256, 4) void probe_valu(
    const float* __restrict__ pred, const int* __restrict__ kl,
    const int* __restrict__ rl, float* __restrict__ ws)
{
    const int tid = threadIdx.x, wv = tid >> 6, lane = tid & 63;
    const int quad = lane >> 4, col = lane & 15, c8 = col & 7;
    const bool lowcol = (col < 8);
    const unsigned int cpack = (unsigned)col * 0x00010001u;
    const unsigned int tps[4] = {cpack, cpack + 0x00100010u,
                                 cpack + 0x00200020u, cpack + 0x00300030u};
    const unsigned int hc = (col == 8) ? 0x3F803F80u : 0u;
    const short8 b2c = __builtin_bit_cast(short8, (u32x4){hc, hc, hc, hc});

    f32x4 acc0[4], acc1[4], acc2;
    #pragma unroll
    for (int s = 0; s < 4; ++s) {
        acc0[s] = (f32x4){0.f, 0.f, 0.f, 0.f};
        acc1[s] = (f32x4){0.f, 0.f, 0.f, 0.f};
    }
    acc2 = (f32x4){0.f, 0.f, 0.f, 0.f};
    float f2 = 0.f;

    const int P0 = blockIdx.x * CHUNK;
    const int pbase = (2 * wv) * 32 + quad * 8;
    Frag A;
    loadf0(A, pred + (size_t)c8 * NPIX + P0 + pbase, kl + P0 + pbase,
           rl + P0 + pbase);

    #pragma unroll 4
    for (int it = 0; it < 32; ++it)
        compute32(A, lowcol, cpack, tps, b2c, acc0, acc1, acc2, f2);

    float s = f2;
    #pragma unroll
    for (int t = 0; t < 4; ++t)
        #pragma unroll
        for (int i = 0; i < 4; ++i) s += acc0[t][i] + acc1[t][i];
    #pragma unroll
    for (int i = 0; i < 4; ++i) s += acc2[i];
    #pragma unroll
    for (int off = 32; off > 0; off >>= 1) s += __shfl_down(s, off, 64);
    if (lane == 0) atomicAdd(&ws[wv], s);
}

// ---------- REAL kernel: exact R3 version (best measured: 84.4 us, absmax 0)
__global__ __launch_bounds__(256, 4) void agg_mfma(
    const float* __restrict__ pred,
    const int*   __restrict__ kl,
    const int*   __restrict__ rl,
    float* __restrict__ ws)
{
    __shared__ float red[LDS_RED];
    __shared__ float s_f2w[4];

    const int tid  = threadIdx.x;
    const int wv   = tid >> 6;
    const int lane = tid & 63;
    const int quad = lane >> 4;
    const int col  = lane & 15;
    const int c8   = col & 7;
    const bool lowcol = (col < 8);
    const unsigned int cpack = (unsigned)col * 0x00010001u;
    const unsigned int tps[4] = {cpack, cpack + 0x00100010u,
                                 cpack + 0x00200020u, cpack + 0x00300030u};
    const unsigned int hc = (col == 8) ? 0x3F803F80u : 0u;
    const short8 b2c = __builtin_bit_cast(short8, (u32x4){hc, hc, hc, hc});

    f32x4 acc0[4], acc1[4], acc2;
    #pragma unroll
    for (int s = 0; s < 4; ++s) {
        acc0[s] = (f32x4){0.f, 0.f, 0.f, 0.f};
        acc1[s] = (f32x4){0.f, 0.f, 0.f, 0.f};
    }
    acc2 = (f32x4){0.f, 0.f, 0.f, 0.f};
    float f2 = 0.f;

    const int P0 = blockIdx.x * CHUNK;
    const int pbase = (2 * wv) * 32 + quad * 8;
    const float* pp = pred + (size_t)c8 * NPIX + P0 + pbase;
    const int*   kp = kl + P0 + pbase;
    const int*   rp = rl + P0 + pbase;

    #pragma unroll 4
    for (int s = 0; s < NSTEP; ++s) {
        #pragma unroll
        for (int i = 0; i < 2; ++i) {
            const int off = s * SPX + i * 32;
            const float4 pa  = *(const float4*)(pp + off);
            const float4 pb4 = *(const float4*)(pp + off + 4);
            const int4   ka  = *(const int4*)(kp + off);
            const int4   kb  = *(const int4*)(kp + off + 4);
            const int4   ra  = *(const int4*)(rp + off);
            const int4   rb  = *(const int4*)(rp + off + 4);

            const int   klv[8] = {ka.x, ka.y, ka.z, ka.w, kb.x, kb.y, kb.z, kb.w};
            const int   rlv[8] = {ra.x, ra.y, ra.z, ra.w, rb.x, rb.y, rb.z, rb.w};
            const float pv[8]  = {pa.x, pa.y, pa.z, pa.w, pb4.x, pb4.y, pb4.z, pb4.w};

            float pr[8];
            #pragma unroll
            for (int j = 0; j < 8; ++j) {
                pr[j] = (rlv[j] > 0) ? pv[j] : 0.f;
                f2 = fmaf(pr[j], pr[j], f2);
            }
            unsigned int b1p[4], kp4[4], rp4[4];
            #pragma unroll
            for (int q = 0; q < 4; ++q) {
                const int j0 = 2 * q, j1 = 2 * q + 1;
                const unsigned int plo = pk_trunc_bf16(pv[j0], pv[j1]);
                const unsigned int phi = pk_trunc_bf16(pr[j0], pr[j1]);
                b1p[q] = lowcol ? plo : phi;
                kp4[q] = pk_lab(klv[j0], klv[j1]);
                rp4[q] = pk_lab(rlv[j0], rlv[j1]);
            }
            const short8 b1 = __builtin_bit_cast(short8,
                (u32x4){b1p[0], b1p[1], b1p[2], b1p[3]});

            #pragma unroll
            for (int t = 0; t < 4; ++t) {
                u32x4 oh;
                #pragma unroll
                for (int q = 0; q < 4; ++q) oh[q] = onehot2(kp4[q], tps[t]);
                const short8 ak = __builtin_bit_cast(short8, oh);
                acc0[t] = __builtin_amdgcn_mfma_f32_16x16x32_bf16(ak, b1,  acc0[t], 0, 0, 0);
                acc1[t] = __builtin_amdgcn_mfma_f32_16x16x32_bf16(ak, b2c, acc1[t], 0, 0, 0);
            }
            u32x4 alo, bhi;
            #pragma unroll
            for (int q = 0; q < 4; ++q) {
                alo[q] = onehot2(rp4[q] & 0x000F000Fu, cpack);
                bhi[q] = onehot2((rp4[q] >> 4) & 0x00030003u, cpack);
            }
            acc2 = __builtin_amdgcn_mfma_f32_16x16x32_bf16(
                __builtin_bit_cast(short8, alo), __builtin_bit_cast(short8, bhi),
                acc2, 0, 0, 0);
        }
    }

    #pragma unroll
    for (int off = 32; off > 0; off >>= 1) f2 += __shfl_down(f2, off, 64);
    if (lane == 0) s_f2w[wv] = f2;

    __syncthreads();
    for (int w = 0; w < 4; ++w) {
        if (wv == w) {
            #pragma unroll
            for (int t = 0; t < 4; ++t)
                #pragma unroll
                for (int i = 0; i < 4; ++i) {
                    const int l = t * 16 + quad * 4 + i;
                    const int a0 = l * 17 + col;
                    const int a1 = L_T1 + l * 17 + col;
                    if (w == 0) { red[a0] = acc0[t][i]; red[a1] = acc1[t][i]; }
                    else        { red[a0] += acc0[t][i]; red[a1] += acc1[t][i]; }
                }
            #pragma unroll
            for (int i = 0; i < 4; ++i) {
                const int a2 = L_T2 + (quad * 4 + i) * 17 + col;
                if (w == 0) red[a2] = acc2[i]; else red[a2] += acc2[i];
            }
        }
        __syncthreads();
    }
    float* wsr = ws + (size_t)(blockIdx.x & (NREP - 1)) * RSTRIDE;
    if (tid == 0)
        atomicAdd(&wsr[WS_F2], s_f2w[0] + s_f2w[1] + s_f2w[2] + s_f2w[3]);
    for (int idx = tid; idx < 2304; idx += 256) {
        int a;
        if (idx < 1024)      a = (idx >> 4) * 17 + (idx & 15);
        else if (idx < 2048) a = L_T1 + ((idx - 1024) >> 4) * 17 + (idx & 15);
        else                 a = L_T2 + ((idx - 2048) >> 4) * 17 + (idx & 15);
        atomicAdd(&wsr[idx], red[a]);
    }
}

__global__ __launch_bounds__(256) void agg_reduce(float* __restrict__ ws)
{
    const int i = blockIdx.x * 256 + threadIdx.x;
    if (i >= WS_FLOATS) return;
    float s = ws[i];
    #pragma unroll 4
    for (int r = 1; r < NREP; ++r) s += ws[i + (size_t)r * RSTRIDE];
    ws[i] = s;
}

__global__ __launch_bounds__(64) void agg_final(const float* __restrict__ ws,
                                                float* __restrict__ out)
{
    const int l = threadIdx.x;
    const float* t0 = ws + l * 16;
    const float pck = 0.5f  * ws[WS_T1 + l * 16 + 8];
    const float pcr = 0.25f * ws[WS_T2 + (l & 15) * 16 + (l >> 4)];

    float corr = 0.f;
    if (l > 0) {
        #pragma unroll
        for (int c = 0; c < 8; ++c) {
            const float seg = 0.5f * t0[c];
            const float T   = 0.5f * t0[8 + c];
            const float gk  = seg / (pck + 1.f);
            corr += gk * (gk * pck - 2.f * T);
        }
    }
    const float rcard = (l > 0) ? pcr : 0.f;
    float S = pcr / (rcard + 1.f);
    int mx = (pcr > 0.5f) ? l : 0;
    float f2 = (l == 0) ? 0.5f * ws[WS_F2] : 0.f;

    #pragma unroll
    for (int off = 32; off > 0; off >>= 1) {
        f2   += __shfl_down(f2, off, 64);
        corr += __shfl_down(corr, off, 64);
        S    += __shfl_down(S, off, 64);
        mx    = max(mx, __shfl_down(mx, off, 64));
    }
    if (l == 0) {
        const float SS = f2 + corr;
        float D = sqrtf(fmaxf(SS, 0.f)) - 0.5f;
        D = fmaxf(D, 0.f);
        out[0] = logf(D * D + 1.f) * S / (float)max(mx, 1);
    }
}

extern "C" void kernel_launch(void* const* d_in, const int* in_sizes, int n_in,
                              void* d_out, int out_size, void* d_ws, size_t ws_size,
                              hipStream_t stream) {
    const float* pred = (const float*)d_in[0];
    const int* kl = (const int*)d_in[3];
    const int* rl = (const int*)d_in[4];
    float* ws = (float*)d_ws;

    // Diagnostic probes run BEFORE the memset: their ws writes are erased,
    // so the real pipeline below is bit-identical to R3's.
    probe_loads<<<NBLOCKS, 256, 0, stream>>>(pred, kl, rl, ws);
    probe_valu <<<NBLOCKS, 256, 0, stream>>>(pred, kl, rl, ws);

    hipMemsetAsync(d_ws, 0, (size_t)NREP * RSTRIDE * sizeof(float), stream);
    agg_mfma<<<NBLOCKS, 256, 0, stream>>>(pred, kl, rl, ws);
    agg_reduce<<<(WS_FLOATS + 255) / 256, 256, 0, stream>>>(ws);
    agg_final<<<1, 64, 0, stream>>>(ws, (float*)d_out);
}

// Round 8
// 257.283 us; speedup vs baseline: 1.4762x; 1.4762x over previous
//
#include <hip/hip_runtime.h>
#include <math.h>

#define NPIX (2048*2048)
#define NBLOCKS 1024           // 4 blocks/CU, all resident in one round
#define CHUNK (NPIX/NBLOCKS)   // 4096 px per block
#define SPX 256
#define NIT 32                 // i-iters per wave (t = 0..31), OFFI(t) pixel order = R3

// global ws: NREP replicas of the 2305-float accumulator table (proven layout)
#define WS_T1 1024
#define WS_T2 2048
#define WS_F2 2304
#define WS_FLOATS 2305
#define NREP 32
#define RSTRIDE 2432
#define L_T1 1088
#define L_T2 2176
#define LDS_RED (2176 + 16*17)

typedef __attribute__((ext_vector_type(8))) short short8;
typedef __attribute__((ext_vector_type(4))) float f32x4;
typedef __attribute__((ext_vector_type(4))) unsigned int u32x4;

__device__ __forceinline__ unsigned int pk_trunc_bf16(float lo, float hi) {
    return __builtin_amdgcn_perm(__float_as_uint(hi), __float_as_uint(lo), 0x07060302u);
}
__device__ __forceinline__ unsigned int pk_lab(int lo, int hi) {
    return __builtin_amdgcn_perm((unsigned)hi, (unsigned)lo, 0x05040100u);
}
__device__ __forceinline__ unsigned int onehot2(unsigned int x, unsigned int tp) {
    const unsigned int a = x ^ tp;
    const unsigned int t = 0x40004000u - a;
    return t & 0x40004000u;
}

// asm-pinned 16B load: volatile -> cannot be sunk/reordered by the scheduler.
__device__ __forceinline__ void gld4(u32x4& d, const void* a) {
    asm volatile("global_load_dwordx4 %0, %1, off" : "=v"(d) : "v"(a));
}
// counted wait + scheduling fence (rule #18: sched_barrier right after waitcnt)
#define ASM_WAITVM(n) do { asm volatile("s_waitcnt vmcnt(" #n ")"); \
                           __builtin_amdgcn_sched_barrier(0); } while (0)

#define OFFI(t) (((t) >> 1) * SPX + ((t) & 1) * 32)

// issue one i-iter's 6 loads into the named register set P{0..5}
#define ISSUE6(P, off_) do { \
    gld4(P##0, pp + (off_));     gld4(P##1, pp + (off_) + 4); \
    gld4(P##2, kp + (off_));     gld4(P##3, kp + (off_) + 4); \
    gld4(P##4, rp + (off_));     gld4(P##5, rp + (off_) + 4); } while (0)

// identical arithmetic/order to R3's loop body, fed from u32x4 register sets
__device__ __forceinline__ void compute32u(
    const u32x4& Pa, const u32x4& Pb, const u32x4& Ka, const u32x4& Kb,
    const u32x4& Ra, const u32x4& Rb,
    bool lowcol, unsigned int cpack, const unsigned int (&tps)[4],
    const short8& b2c, f32x4 (&acc0)[4], f32x4 (&acc1)[4], f32x4& acc2,
    float& f2)
{
    int klv[8], rlv[8]; float pv[8];
    #pragma unroll
    for (int j = 0; j < 4; ++j) {
        klv[j] = (int)Ka[j]; klv[4 + j] = (int)Kb[j];
        rlv[j] = (int)Ra[j]; rlv[4 + j] = (int)Rb[j];
        pv[j] = __uint_as_float(Pa[j]); pv[4 + j] = __uint_as_float(Pb[j]);
    }
    float pr[8];
    #pragma unroll
    for (int j = 0; j < 8; ++j) {
        pr[j] = (rlv[j] > 0) ? pv[j] : 0.f;
        f2 = fmaf(pr[j], pr[j], f2);          // exact f32 sum of pr^2
    }
    unsigned int b1p[4], kp4[4], rp4[4];
    #pragma unroll
    for (int q = 0; q < 4; ++q) {
        const int j0 = 2 * q, j1 = 2 * q + 1;
        const unsigned int plo = pk_trunc_bf16(pv[j0], pv[j1]);
        const unsigned int phi = pk_trunc_bf16(pr[j0], pr[j1]);
        b1p[q] = lowcol ? plo : phi;
        kp4[q] = pk_lab(klv[j0], klv[j1]);
        rp4[q] = pk_lab(rlv[j0], rlv[j1]);
    }
    const short8 b1 = __builtin_bit_cast(short8,
        (u32x4){b1p[0], b1p[1], b1p[2], b1p[3]});
    #pragma unroll
    for (int t = 0; t < 4; ++t) {             // T0 + T1 share ohk
        u32x4 oh;
        #pragma unroll
        for (int q = 0; q < 4; ++q) oh[q] = onehot2(kp4[q], tps[t]);
        const short8 ak = __builtin_bit_cast(short8, oh);
        acc0[t] = __builtin_amdgcn_mfma_f32_16x16x32_bf16(ak, b1,  acc0[t], 0, 0, 0);
        acc1[t] = __builtin_amdgcn_mfma_f32_16x16x32_bf16(ak, b2c, acc1[t], 0, 0, 0);
    }
    u32x4 alo, bhi;                           // T2 radix: 1 MFMA
    #pragma unroll
    for (int q = 0; q < 4; ++q) {
        alo[q] = onehot2(rp4[q] & 0x000F000Fu, cpack);
        bhi[q] = onehot2((rp4[q] >> 4) & 0x00030003u, cpack);
    }
    acc2 = __builtin_amdgcn_mfma_f32_16x16x32_bf16(
        __builtin_bit_cast(short8, alo), __builtin_bit_cast(short8, bhi),
        acc2, 0, 0, 0);
}

__global__ __launch_bounds__(256, 4) void agg_mfma(
    const float* __restrict__ pred,
    const int*   __restrict__ kl,
    const int*   __restrict__ rl,
    float* __restrict__ ws)
{
    __shared__ float red[LDS_RED];
    __shared__ float s_f2w[4];

    const int tid  = threadIdx.x;
    const int wv   = tid >> 6;
    const int lane = tid & 63;
    const int quad = lane >> 4;
    const int col  = lane & 15;
    const int c8   = col & 7;
    const bool lowcol = (col < 8);
    const unsigned int cpack = (unsigned)col * 0x00010001u;
    const unsigned int tps[4] = {cpack, cpack + 0x00100010u,
                                 cpack + 0x00200020u, cpack + 0x00300030u};
    const unsigned int hc = (col == 8) ? 0x3F803F80u : 0u;
    const short8 b2c = __builtin_bit_cast(short8, (u32x4){hc, hc, hc, hc});

    f32x4 acc0[4], acc1[4], acc2;
    #pragma unroll
    for (int s = 0; s < 4; ++s) {
        acc0[s] = (f32x4){0.f, 0.f, 0.f, 0.f};
        acc1[s] = (f32x4){0.f, 0.f, 0.f, 0.f};
    }
    acc2 = (f32x4){0.f, 0.f, 0.f, 0.f};
    float f2 = 0.f;

    const int P0 = blockIdx.x * CHUNK;
    const int pbase = (2 * wv) * 32 + quad * 8;
    const float* pp = pred + (size_t)c8 * NPIX + P0 + pbase;
    const int*   kp = kl + P0 + pbase;
    const int*   rp = rl + P0 + pbase;

    // Forced depth-2 memory pipeline (asm loads cannot be sunk; counted
    // vmcnt keeps 12 loads in flight per wave at all times).
    u32x4 A0, A1, A2, A3, A4, A5;
    u32x4 B0, B1, B2, B3, B4, B5;
    ISSUE6(A, OFFI(0));
    ISSUE6(B, OFFI(1));

    #pragma unroll 1
    for (int k = 0; k < 15; ++k) {
        ASM_WAITVM(6);            // A(2k) landed; B(2k+1) still in flight
        compute32u(A0, A1, A2, A3, A4, A5, lowcol, cpack, tps, b2c,
                   acc0, acc1, acc2, f2);
        ISSUE6(A, (k + 1) * SPX);             // t = 2k+2
        ASM_WAITVM(6);            // B(2k+1) landed; A(2k+2) in flight
        compute32u(B0, B1, B2, B3, B4, B5, lowcol, cpack, tps, b2c,
                   acc0, acc1, acc2, f2);
        ISSUE6(B, (k + 1) * SPX + 32);        // t = 2k+3
    }
    ASM_WAITVM(6);                // A(30)
    compute32u(A0, A1, A2, A3, A4, A5, lowcol, cpack, tps, b2c,
               acc0, acc1, acc2, f2);
    ASM_WAITVM(0);                // B(31)
    compute32u(B0, B1, B2, B3, B4, B5, lowcol, cpack, tps, b2c,
               acc0, acc1, acc2, f2);

    // --- f2: wave shuffle reduce
    #pragma unroll
    for (int off = 32; off > 0; off >>= 1) f2 += __shfl_down(f2, off, 64);
    if (lane == 0) s_f2w[wv] = f2;

    // --- cross-wave reduce, phased RMW
    __syncthreads();
    for (int w = 0; w < 4; ++w) {
        if (wv == w) {
            #pragma unroll
            for (int t = 0; t < 4; ++t)
                #pragma unroll
                for (int i = 0; i < 4; ++i) {
                    const int l = t * 16 + quad * 4 + i;
                    const int a0 = l * 17 + col;
                    const int a1 = L_T1 + l * 17 + col;
                    if (w == 0) { red[a0] = acc0[t][i]; red[a1] = acc1[t][i]; }
                    else        { red[a0] += acc0[t][i]; red[a1] += acc1[t][i]; }
                }
            #pragma unroll
            for (int i = 0; i < 4; ++i) {
                const int a2 = L_T2 + (quad * 4 + i) * 17 + col;
                if (w == 0) red[a2] = acc2[i]; else red[a2] += acc2[i];
            }
        }
        __syncthreads();
    }
    float* wsr = ws + (size_t)(blockIdx.x & (NREP - 1)) * RSTRIDE;
    if (tid == 0)
        atomicAdd(&wsr[WS_F2], s_f2w[0] + s_f2w[1] + s_f2w[2] + s_f2w[3]);
    for (int idx = tid; idx < 2304; idx += 256) {
        int a;
        if (idx < 1024)      a = (idx >> 4) * 17 + (idx & 15);
        else if (idx < 2048) a = L_T1 + ((idx - 1024) >> 4) * 17 + (idx & 15);
        else                 a = L_T2 + ((idx - 2048) >> 4) * 17 + (idx & 15);
        atomicAdd(&wsr[idx], red[a]);
    }
}

// fold NREP replicas into replica 0 (L2-hot)
__global__ __launch_bounds__(256) void agg_reduce(float* __restrict__ ws)
{
    const int i = blockIdx.x * 256 + threadIdx.x;
    if (i >= WS_FLOATS) return;
    float s = ws[i];
    #pragma unroll 4
    for (int r = 1; r < NREP; ++r) s += ws[i + (size_t)r * RSTRIDE];
    ws[i] = s;
}

__global__ __launch_bounds__(64) void agg_final(const float* __restrict__ ws,
                                                float* __restrict__ out)
{
    const int l = threadIdx.x;
    const float* t0 = ws + l * 16;
    const float pck = 0.5f  * ws[WS_T1 + l * 16 + 8];
    const float pcr = 0.25f * ws[WS_T2 + (l & 15) * 16 + (l >> 4)];

    float corr = 0.f;
    if (l > 0) {
        #pragma unroll
        for (int c = 0; c < 8; ++c) {
            const float seg = 0.5f * t0[c];
            const float T   = 0.5f * t0[8 + c];
            const float gk  = seg / (pck + 1.f);
            corr += gk * (gk * pck - 2.f * T);
        }
    }
    const float rcard = (l > 0) ? pcr : 0.f;
    float S = pcr / (rcard + 1.f);
    int mx = (pcr > 0.5f) ? l : 0;
    float f2 = (l == 0) ? 0.5f * ws[WS_F2] : 0.f;

    #pragma unroll
    for (int off = 32; off > 0; off >>= 1) {
        f2   += __shfl_down(f2, off, 64);
        corr += __shfl_down(corr, off, 64);
        S    += __shfl_down(S, off, 64);
        mx    = max(mx, __shfl_down(mx, off, 64));
    }
    if (l == 0) {
        const float SS = f2 + corr;
        float D = sqrtf(fmaxf(SS, 0.f)) - 0.5f;
        D = fmaxf(D, 0.f);
        out[0] = logf(D * D + 1.f) * S / (float)max(mx, 1);
    }
}

extern "C" void kernel_launch(void* const* d_in, const int* in_sizes, int n_in,
                              void* d_out, int out_size, void* d_ws, size_t ws_size,
                              hipStream_t stream) {
    const float* pred = (const float*)d_in[0];
    const int* kl = (const int*)d_in[3];
    const int* rl = (const int*)d_in[4];
    float* ws = (float*)d_ws;

    hipMemsetAsync(d_ws, 0, (size_t)NREP * RSTRIDE * sizeof(float), stream);
    agg_mfma<<<NBLOCKS, 256, 0, stream>>>(pred, kl, rl, ws);
    agg_reduce<<<(WS_FLOATS + 255) / 256, 256, 0, stream>>>(ws);
    agg_final<<<1, 64, 0, stream>>>(ws, (float*)d_out);
}